// Round 3
// baseline (377.013 us; speedup 1.0000x reference)
//
#include <hip/hip_runtime.h>
#include <hip/hip_bf16.h>

// Problem constants
#define B_    8
#define C_    64
#define P_    64
#define H_    256
#define W_    256
#define BHW_  (B_ * H_ * W_)   // 524288
#define BN_EPS 1e-5f

// Chain tiling: 8 channels/launch, 16x32 interior, halo 8 -> 32x48 tile.
// 1024 blocks (4/CU) for barrier-latency overlap.
#define CHUNK 8
#define TROWS 32               // tile rows (16 interior + 2*8 halo)
#define TCOLS 48               // tile cols (32 interior + 2*8 halo)
#define SWC   52               // LDS row stride (floats)
#define NT    384              // 32 rows x 12 segs of 4 px
#define BUFSZ ((TROWS + 2) * SWC + 8)

// ---------------------------------------------------------------------------
// Chain kernel: one float4 row-segment per thread, fixed position across 8
// sequential conv steps. Validity: cell at tile-edge distance d is valid
// after step i iff d >= i+1; interior (d>=8) valid through step 7. Garbage
// in the shrinking halo ring is finite (fmax kills NaN, clamp bounds) and
// never read by valid cells. Out-of-image cells forced to 0 every step.
// ---------------------------------------------------------------------------
__global__ __launch_bounds__(NT) void chain_kernel(
    const float* __restrict__ src,   // previous-channel image slab base
    size_t src_batch_stride,         // C_*H_*W_ for x, H_*W_ for ys slab
    const float* __restrict__ dw,    // dw_w + c0*9
    float* __restrict__ ys,          // ys base (C,B,H,W)
    int c0)
{
    __shared__ float buf0[BUFSZ];
    __shared__ float buf1[BUFSZ];

    const int tid = threadIdx.x;
    const int b   = blockIdx.z;
    const int ty0 = blockIdx.y * 16;
    const int tx0 = blockIdx.x * 32;
    const int row = tid / 12;          // 0..31
    const int seg = tid - row * 12;    // 0..11
    const int lx  = seg * 4;           // 0..44
    const int gy  = ty0 - 8 + row;
    const int gx  = tx0 - 8 + lx;      // multiple of 4 -> aligned float4
    const bool inImg = (gy >= 0) && (gy < H_) && (gx >= 0) && (gx < W_);
    const float msk = inImg ? 1.0f : 0.0f;

    // initial tile load (zero outside image)
    float4 v = make_float4(0.f, 0.f, 0.f, 0.f);
    if (inImg)
        v = *(const float4*)(src + (size_t)b * src_batch_stride
                             + (size_t)gy * W_ + gx);

    float* cur = buf0;
    float* nxt = buf1;
    const int cell = (row + 1) * SWC + 4 + lx;   // +1 row pad, +4 col pad
    *(float4*)&cur[cell] = v;
    __syncthreads();

    const bool wOK = (row >= 8) && (row < 24) && (seg >= 2) && (seg < 10);
    float* gbase = ys + (size_t)c0 * BHW_ + ((size_t)b * H_ + gy) * W_ + gx;

    for (int i = 0; i < CHUNK; ++i) {
        const float w0 = dw[i*9+0], w1 = dw[i*9+1], w2 = dw[i*9+2];
        const float w3 = dw[i*9+3], w4 = dw[i*9+4], w5 = dw[i*9+5];
        const float w6 = dw[i*9+6], w7 = dw[i*9+7], w8 = dw[i*9+8];

        const int ro = row * SWC + 4 + lx;       // (row-1, lx) in padded space

        // three 6-wide rows via bank-balanced float2 reads
        float a[6], e[6], c[6];
        {
            const float* rp = &cur[ro];
            float2 q0 = *(const float2*)(rp - 2);
            float2 q1 = *(const float2*)(rp);
            float2 q2 = *(const float2*)(rp + 2);
            float2 q3 = *(const float2*)(rp + 4);
            a[0]=q0.y; a[1]=q1.x; a[2]=q1.y; a[3]=q2.x; a[4]=q2.y; a[5]=q3.x;
        }
        {
            const float* rp = &cur[ro + SWC];
            float2 q0 = *(const float2*)(rp - 2);
            float2 q1 = *(const float2*)(rp);
            float2 q2 = *(const float2*)(rp + 2);
            float2 q3 = *(const float2*)(rp + 4);
            e[0]=q0.y; e[1]=q1.x; e[2]=q1.y; e[3]=q2.x; e[4]=q2.y; e[5]=q3.x;
        }
        {
            const float* rp = &cur[ro + 2 * SWC];
            float2 q0 = *(const float2*)(rp - 2);
            float2 q1 = *(const float2*)(rp);
            float2 q2 = *(const float2*)(rp + 2);
            float2 q3 = *(const float2*)(rp + 4);
            c[0]=q0.y; c[1]=q1.x; c[2]=q1.y; c[3]=q2.x; c[4]=q2.y; c[5]=q3.x;
        }

        float o[4];
#pragma unroll
        for (int j = 0; j < 4; ++j) {
            float s = fmaf(a[j],   w0,
                      fmaf(a[j+1], w1,
                      fmaf(a[j+2], w2,
                      fmaf(e[j],   w3,
                      fmaf(e[j+1], w4,
                      fmaf(e[j+2], w5,
                      fmaf(c[j],   w6,
                      fmaf(c[j+1], w7,
                           c[j+2] * w8))))))));
            o[j] = fminf(fmaxf(s, 0.f), 6.f) * msk;
        }
        float4 ov = make_float4(o[0], o[1], o[2], o[3]);
        if (wOK)
            *(float4*)(gbase + (size_t)i * BHW_) = ov;
        if (i < CHUNK - 1) {                 // last step: no LDS round-trip
            *(float4*)&nxt[cell] = ov;
            __syncthreads();
            float* t = cur; cur = nxt; nxt = t;
        }
    }
}

// ---------------------------------------------------------------------------
// Fuse kernel, 2 contiguous pixels/thread (float2 y loads).
// ---------------------------------------------------------------------------
__global__ __launch_bounds__(256) void fuse_kernel(
    const float* __restrict__ ys,      // (C, BHW)
    const float* __restrict__ pw_w,    // (P, C)
    const float* __restrict__ gamma,
    const float* __restrict__ beta,
    const float* __restrict__ mean,
    const float* __restrict__ var,
    const float* __restrict__ conv_w,  // (1, P)
    float* __restrict__ out)           // (BHW)
{
    __shared__ float As[C_ * P_];      // As[c*64 + p] = pw_w[p][c] * scale[p]
    __shared__ float bias_s[P_];
    __shared__ float cw_s[P_];

    const int tid = threadIdx.x;

    for (int idx = tid; idx < C_ * P_; idx += 256) {
        int p = idx & 63;
        int c = idx >> 6;
        float scale = gamma[p] / sqrtf(var[p] + BN_EPS);
        As[idx] = pw_w[p * C_ + c] * scale;
    }
    if (tid < P_) {
        float scale = gamma[tid] / sqrtf(var[tid] + BN_EPS);
        bias_s[tid] = beta[tid] - mean[tid] * scale;
        cw_s[tid]   = conv_w[tid];
    }
    __syncthreads();

    const size_t n0 = ((size_t)blockIdx.x * 256 + tid) * 2;

    float h0[P_], h1[P_];
#pragma unroll
    for (int p = 0; p < P_; ++p) { h0[p] = 0.f; h1[p] = 0.f; }

#pragma unroll 2
    for (int c = 0; c < C_; ++c) {
        float2 y = *(const float2*)(ys + (size_t)c * BHW_ + n0);
        const float* arow = &As[c * P_];
#pragma unroll
        for (int p = 0; p < P_; ++p) {
            float av = arow[p];
            h0[p] = fmaf(av, y.x, h0[p]);
            h1[p] = fmaf(av, y.y, h1[p]);
        }
    }

    float acc0 = 0.f, acc1 = 0.f;
#pragma unroll
    for (int p = 0; p < P_; ++p) {
        float v0 = fminf(fmaxf(h0[p] + bias_s[p], 0.f), 6.f);
        float v1 = fminf(fmaxf(h1[p] + bias_s[p], 0.f), 6.f);
        acc0 = fmaf(cw_s[p], v0, acc0);
        acc1 = fmaf(cw_s[p], v1, acc1);
    }
    *(float2*)(out + n0) = make_float2(acc0, acc1);
}

// ---------------------------------------------------------------------------
extern "C" void kernel_launch(void* const* d_in, const int* in_sizes, int n_in,
                              void* d_out, int out_size, void* d_ws, size_t ws_size,
                              hipStream_t stream) {
    const float* x      = (const float*)d_in[0];   // (B,C,H,W) — only chan 0 used
    const float* dw_w   = (const float*)d_in[1];   // (C,3,3)
    const float* pw_w   = (const float*)d_in[2];   // (P,C)
    const float* gamma  = (const float*)d_in[3];
    const float* beta   = (const float*)d_in[4];
    const float* mean   = (const float*)d_in[5];
    const float* var    = (const float*)d_in[6];
    const float* conv_w = (const float*)d_in[7];   // (1,P)
    float* out = (float*)d_out;

    float* ys = (float*)d_ws;                      // (C, B, H, W) fp32 = 128 MiB

    dim3 cgrid(W_ / 32, H_ / 16, B_);              // 8,16,8 = 1024 blocks

    // chunk 0: seeded by x[:, 0]
    chain_kernel<<<cgrid, NT, 0, stream>>>(
        x, (size_t)C_ * H_ * W_, dw_w, ys, 0);

    // chunks 1..7: seeded by ys[c0-1]
    for (int k = 1; k < C_ / CHUNK; ++k) {
        int c0 = k * CHUNK;
        chain_kernel<<<cgrid, NT, 0, stream>>>(
            ys + (size_t)(c0 - 1) * BHW_, (size_t)H_ * W_,
            dw_w + c0 * 9, ys, c0);
    }

    // fused pointwise + BN + ReLU6 + final 1x1  (2 px/thread)
    fuse_kernel<<<BHW_ / 512, 256, 0, stream>>>(
        ys, pw_w, gamma, beta, mean, var, conv_w, out);
}

// Round 4
// 296.314 us; speedup vs baseline: 1.2723x; 1.2723x over previous
//
#include <hip/hip_runtime.h>
#include <hip/hip_bf16.h>

// Problem constants
#define B_    8
#define C_    64
#define P_    64
#define H_    256
#define W_    256
#define BHW_  (B_ * H_ * W_)   // 524288
#define BN_EPS 1e-5f

// Chain tiling: 16 channels/launch (4 launches), 32x32 interior, halo 16
// -> 64x64 working tile. 1024 threads = 64 rows x 16 float4-segs.
// 512 blocks = 2 blocks/CU = 32 waves/CU (max occupancy).
#define CHUNK 16
#define SWC   64               // LDS row stride (floats); b128 reads are
                               // conflict-free (wave covers 4 rows x 64 cols)

// DPP lane shifts within 16-lane rows. Our 16 segs/tile-row map exactly onto
// one DPP row, so seg+-1 exchange is a free-ish VALU op (no DS port).
__device__ __forceinline__ float dpp_row_shr1(float v) {   // lane n <- n-1
    return __int_as_float(__builtin_amdgcn_update_dpp(
        0, __float_as_int(v), 0x111, 0xF, 0xF, true));
}
__device__ __forceinline__ float dpp_row_shl1(float v) {   // lane n <- n+1
    return __int_as_float(__builtin_amdgcn_update_dpp(
        0, __float_as_int(v), 0x101, 0xF, 0xF, true));
}

// ---------------------------------------------------------------------------
// Chain kernel: 16 sequential 3x3 conv+ReLU6 steps on a 64x64 LDS tile.
// Validity ring: cell at tile-edge distance d is correct after step i iff
// d >= i+1; interior (d>=16) survives all 16 steps. Halo garbage is finite
// (fmax kills NaN, clamp bounds, DPP bound_ctrl=0 fills) and never read by
// valid cells at the step where they're stored. Out-of-image cells forced
// to 0 every step (zero-pad semantics).
// ---------------------------------------------------------------------------
__global__ __launch_bounds__(1024, 8) void chain_kernel(
    const float* __restrict__ src,   // previous-channel image slab base
    size_t src_batch_stride,         // C_*H_*W_ for x, H_*W_ for ys slab
    const float* __restrict__ dw,    // dw_w + c0*9
    float* __restrict__ ys,          // ys base (C,B,H,W)
    int c0)
{
    __shared__ __align__(16) float buf0[66 * SWC];  // 1 pad row top+bottom
    __shared__ __align__(16) float buf1[66 * SWC];

    const int tid = threadIdx.x;
    const int row = tid >> 4;          // 0..63
    const int seg = tid & 15;          // 0..15
    const int lx  = seg * 4;           // 0..60
    const int b   = blockIdx.z;
    const int ty0 = blockIdx.y * 32;
    const int tx0 = blockIdx.x * 32;
    const int gy  = ty0 - 16 + row;
    const int gx  = tx0 - 16 + lx;     // multiple of 4 -> aligned float4
    const bool inImg = (gy >= 0) && (gy < H_) && (gx >= 0) && (gx < W_);
    const float msk = inImg ? 1.0f : 0.0f;

    // initial tile load (zero outside image)
    float4 v = make_float4(0.f, 0.f, 0.f, 0.f);
    if (inImg)
        v = *(const float4*)(src + (size_t)b * src_batch_stride
                             + (size_t)gy * W_ + gx);

    float* cur = buf0;
    float* nxt = buf1;
    const int cell = (row + 1) * SWC + lx;   // +1 pad row
    *(float4*)&cur[cell] = v;
    if (row == 0) {                          // zero both pad rows, both bufs
        float4 z = make_float4(0.f, 0.f, 0.f, 0.f);
        *(float4*)&buf0[lx] = z;  *(float4*)&buf0[65 * SWC + lx] = z;
        *(float4*)&buf1[lx] = z;  *(float4*)&buf1[65 * SWC + lx] = z;
    }
    __syncthreads();

    const bool wOK = (row >= 16) && (row < 48) && (seg >= 4) && (seg < 12);
    float* gbase = ys + (size_t)c0 * BHW_ + ((size_t)b * H_ + gy) * W_ + gx;

    for (int i = 0; i < CHUNK; ++i) {
        const float w0 = dw[i*9+0], w1 = dw[i*9+1], w2 = dw[i*9+2];
        const float w3 = dw[i*9+3], w4 = dw[i*9+4], w5 = dw[i*9+5];
        const float w6 = dw[i*9+6], w7 = dw[i*9+7], w8 = dw[i*9+8];

        // three aligned b128 reads: rows above/at/below own cells
        float4 rT = *(const float4*)&cur[cell - SWC];
        float4 rM = *(const float4*)&cur[cell];
        float4 rB = *(const float4*)&cur[cell + SWC];

        // 6-wide windows via DPP neighbor exchange (cols lx-1 .. lx+4)
        float t[6], m[6], bo[6];
        t[0]  = dpp_row_shr1(rT.w); t[1]=rT.x; t[2]=rT.y; t[3]=rT.z; t[4]=rT.w;
        t[5]  = dpp_row_shl1(rT.x);
        m[0]  = dpp_row_shr1(rM.w); m[1]=rM.x; m[2]=rM.y; m[3]=rM.z; m[4]=rM.w;
        m[5]  = dpp_row_shl1(rM.x);
        bo[0] = dpp_row_shr1(rB.w); bo[1]=rB.x; bo[2]=rB.y; bo[3]=rB.z; bo[4]=rB.w;
        bo[5] = dpp_row_shl1(rB.x);

        float o[4];
#pragma unroll
        for (int j = 0; j < 4; ++j) {
            float s = fmaf(t[j],    w0,
                      fmaf(t[j+1],  w1,
                      fmaf(t[j+2],  w2,
                      fmaf(m[j],    w3,
                      fmaf(m[j+1],  w4,
                      fmaf(m[j+2],  w5,
                      fmaf(bo[j],   w6,
                      fmaf(bo[j+1], w7,
                           bo[j+2] * w8))))))));
            o[j] = fminf(fmaxf(s, 0.f), 6.f) * msk;
        }
        float4 ov = make_float4(o[0], o[1], o[2], o[3]);
        if (wOK)
            *(float4*)(gbase + (size_t)i * BHW_) = ov;
        if (i < CHUNK - 1) {
            *(float4*)&nxt[cell] = ov;
            __syncthreads();
            float* tmp = cur; cur = nxt; nxt = tmp;
        }
    }
}

// ---------------------------------------------------------------------------
// Fuse kernel, 2 pixels/thread (round-2 form — best measured).
// ---------------------------------------------------------------------------
__global__ __launch_bounds__(256) void fuse_kernel(
    const float* __restrict__ ys,      // (C, BHW)
    const float* __restrict__ pw_w,    // (P, C)
    const float* __restrict__ gamma,
    const float* __restrict__ beta,
    const float* __restrict__ mean,
    const float* __restrict__ var,
    const float* __restrict__ conv_w,  // (1, P)
    float* __restrict__ out)           // (BHW)
{
    __shared__ float As[C_ * P_];      // As[c*64 + p] = pw_w[p][c] * scale[p]
    __shared__ float bias_s[P_];
    __shared__ float cw_s[P_];

    const int tid = threadIdx.x;

    for (int idx = tid; idx < C_ * P_; idx += 256) {
        int p = idx & 63;
        int c = idx >> 6;
        float scale = gamma[p] / sqrtf(var[p] + BN_EPS);
        As[idx] = pw_w[p * C_ + c] * scale;
    }
    if (tid < P_) {
        float scale = gamma[tid] / sqrtf(var[tid] + BN_EPS);
        bias_s[tid] = beta[tid] - mean[tid] * scale;
        cw_s[tid]   = conv_w[tid];
    }
    __syncthreads();

    const size_t n0 = (size_t)blockIdx.x * 512 + tid;
    const size_t n1 = n0 + 256;

    float h0[P_], h1[P_];
#pragma unroll
    for (int p = 0; p < P_; ++p) { h0[p] = 0.f; h1[p] = 0.f; }

#pragma unroll 2
    for (int c = 0; c < C_; ++c) {
        float y0 = ys[(size_t)c * BHW_ + n0];
        float y1 = ys[(size_t)c * BHW_ + n1];
        const float* arow = &As[c * P_];
#pragma unroll
        for (int p = 0; p < P_; ++p) {
            float av = arow[p];
            h0[p] = fmaf(av, y0, h0[p]);
            h1[p] = fmaf(av, y1, h1[p]);
        }
    }

    float acc0 = 0.f, acc1 = 0.f;
#pragma unroll
    for (int p = 0; p < P_; ++p) {
        float v0 = fminf(fmaxf(h0[p] + bias_s[p], 0.f), 6.f);
        float v1 = fminf(fmaxf(h1[p] + bias_s[p], 0.f), 6.f);
        acc0 = fmaf(cw_s[p], v0, acc0);
        acc1 = fmaf(cw_s[p], v1, acc1);
    }
    out[n0] = acc0;
    out[n1] = acc1;
}

// ---------------------------------------------------------------------------
extern "C" void kernel_launch(void* const* d_in, const int* in_sizes, int n_in,
                              void* d_out, int out_size, void* d_ws, size_t ws_size,
                              hipStream_t stream) {
    const float* x      = (const float*)d_in[0];   // (B,C,H,W) — only chan 0 used
    const float* dw_w   = (const float*)d_in[1];   // (C,3,3)
    const float* pw_w   = (const float*)d_in[2];   // (P,C)
    const float* gamma  = (const float*)d_in[3];
    const float* beta   = (const float*)d_in[4];
    const float* mean   = (const float*)d_in[5];
    const float* var    = (const float*)d_in[6];
    const float* conv_w = (const float*)d_in[7];   // (1,P)
    float* out = (float*)d_out;

    float* ys = (float*)d_ws;                      // (C, B, H, W) fp32 = 128 MiB

    dim3 cgrid(W_ / 32, H_ / 32, B_);              // 8,8,8 = 512 blocks

    // chunk 0: seeded by x[:, 0]
    chain_kernel<<<cgrid, 1024, 0, stream>>>(
        x, (size_t)C_ * H_ * W_, dw_w, ys, 0);

    // chunks 1..3: seeded by ys[c0-1]
    for (int k = 1; k < C_ / CHUNK; ++k) {
        int c0 = k * CHUNK;
        chain_kernel<<<cgrid, 1024, 0, stream>>>(
            ys + (size_t)(c0 - 1) * BHW_, (size_t)H_ * W_,
            dw_w + c0 * 9, ys, c0);
    }

    // fused pointwise + BN + ReLU6 + final 1x1  (2 px/thread)
    fuse_kernel<<<BHW_ / 512, 256, 0, stream>>>(
        ys, pw_w, gamma, beta, mean, var, conv_w, out);
}

// Round 5
// 294.622 us; speedup vs baseline: 1.2797x; 1.0057x over previous
//
#include <hip/hip_runtime.h>
#include <hip/hip_bf16.h>

// Problem constants
#define B_    8
#define C_    64
#define P_    64
#define H_    256
#define W_    256
#define BHW_  (B_ * H_ * W_)   // 524288
#define BN_EPS 1e-5f

// Chain tiling: 16 channels/launch (4 launches), 32x32 interior, halo 16
// -> 64x64 working tile. 1024 threads = 64 rows x 16 float4-segs.
// 512 blocks = 2 blocks/CU = 32 waves/CU (max occupancy).
#define CHUNK 16
#define SWC   64               // LDS row stride (floats)

// DPP lane shifts within 16-lane rows. 16 segs/tile-row = one DPP row, so
// seg+-1 exchange is a VALU op (no DS port).
__device__ __forceinline__ float dpp_row_shr1(float v) {   // lane n <- n-1
    return __int_as_float(__builtin_amdgcn_update_dpp(
        0, __float_as_int(v), 0x111, 0xF, 0xF, true));
}
__device__ __forceinline__ float dpp_row_shl1(float v) {   // lane n <- n+1
    return __int_as_float(__builtin_amdgcn_update_dpp(
        0, __float_as_int(v), 0x101, 0xF, 0xF, true));
}

// ---------------------------------------------------------------------------
// Chain kernel: 16 sequential 3x3 conv+ReLU6 steps on a 64x64 LDS tile.
// Validity ring: cell at tile-edge distance d is correct after step i iff
// d >= i+1; interior (d>=16) survives all 16 steps. Halo garbage is finite
// and never read by valid cells. Out-of-image cells forced to 0 every step.
// KEY CHANGE vs R4: the global ys store for step i is issued AFTER step i's
// barrier (in the shadow of step i+1's compute), so the conservative
// vmcnt(0) drain before each s_barrier no longer serializes an HBM store
// retire into every step.
// ---------------------------------------------------------------------------
__global__ __launch_bounds__(1024, 8) void chain_kernel(
    const float* __restrict__ src,   // previous-channel image slab base
    size_t src_batch_stride,         // C_*H_*W_ for x, H_*W_ for ys slab
    const float* __restrict__ dw,    // dw_w + c0*9
    float* __restrict__ ys,          // ys base (C,B,H,W)
    int c0)
{
    __shared__ __align__(16) float buf0[66 * SWC];  // 1 pad row top+bottom
    __shared__ __align__(16) float buf1[66 * SWC];

    const int tid = threadIdx.x;
    const int row = tid >> 4;          // 0..63
    const int seg = tid & 15;          // 0..15
    const int lx  = seg * 4;           // 0..60
    const int b   = blockIdx.z;
    const int ty0 = blockIdx.y * 32;
    const int tx0 = blockIdx.x * 32;
    const int gy  = ty0 - 16 + row;
    const int gx  = tx0 - 16 + lx;     // multiple of 4 -> aligned float4
    const bool inImg = (gy >= 0) && (gy < H_) && (gx >= 0) && (gx < W_);
    const float msk = inImg ? 1.0f : 0.0f;

    // initial tile load (zero outside image)
    float4 v = make_float4(0.f, 0.f, 0.f, 0.f);
    if (inImg)
        v = *(const float4*)(src + (size_t)b * src_batch_stride
                             + (size_t)gy * W_ + gx);

    float* cur = buf0;
    float* nxt = buf1;
    const int cell = (row + 1) * SWC + lx;   // +1 pad row
    *(float4*)&cur[cell] = v;
    if (row == 0) {                          // zero pad rows, both buffers
        float4 z = make_float4(0.f, 0.f, 0.f, 0.f);
        *(float4*)&buf0[lx] = z;  *(float4*)&buf0[65 * SWC + lx] = z;
        *(float4*)&buf1[lx] = z;  *(float4*)&buf1[65 * SWC + lx] = z;
    }
    __syncthreads();

    const bool wOK = (row >= 16) && (row < 48) && (seg >= 4) && (seg < 12);
    float* gbase = ys + (size_t)c0 * BHW_ + ((size_t)b * H_ + gy) * W_ + gx;

#pragma unroll
    for (int i = 0; i < CHUNK; ++i) {
        const float w0 = dw[i*9+0], w1 = dw[i*9+1], w2 = dw[i*9+2];
        const float w3 = dw[i*9+3], w4 = dw[i*9+4], w5 = dw[i*9+5];
        const float w6 = dw[i*9+6], w7 = dw[i*9+7], w8 = dw[i*9+8];

        // three aligned b128 reads: rows above/at/below own cells
        float4 rT = *(const float4*)&cur[cell - SWC];
        float4 rM = *(const float4*)&cur[cell];
        float4 rB = *(const float4*)&cur[cell + SWC];

        float tl = dpp_row_shr1(rT.w), tr = dpp_row_shl1(rT.x);
        float ml = dpp_row_shr1(rM.w), mr = dpp_row_shl1(rM.x);
        float bl = dpp_row_shr1(rB.w), br = dpp_row_shl1(rB.x);

        float4 ov;
        {
            float s0 = fmaf(tl,   w0, fmaf(rT.x, w1, fmaf(rT.y, w2,
                       fmaf(ml,   w3, fmaf(rM.x, w4, fmaf(rM.y, w5,
                       fmaf(bl,   w6, fmaf(rB.x, w7, rB.y * w8))))))));
            float s1 = fmaf(rT.x, w0, fmaf(rT.y, w1, fmaf(rT.z, w2,
                       fmaf(rM.x, w3, fmaf(rM.y, w4, fmaf(rM.z, w5,
                       fmaf(rB.x, w6, fmaf(rB.y, w7, rB.z * w8))))))));
            float s2 = fmaf(rT.y, w0, fmaf(rT.z, w1, fmaf(rT.w, w2,
                       fmaf(rM.y, w3, fmaf(rM.z, w4, fmaf(rM.w, w5,
                       fmaf(rB.y, w6, fmaf(rB.z, w7, rB.w * w8))))))));
            float s3 = fmaf(rT.z, w0, fmaf(rT.w, w1, fmaf(tr,   w2,
                       fmaf(rM.z, w3, fmaf(rM.w, w4, fmaf(mr,   w5,
                       fmaf(rB.z, w6, fmaf(rB.w, w7, br   * w8))))))));
            ov.x = fminf(fmaxf(s0, 0.f), 6.f) * msk;
            ov.y = fminf(fmaxf(s1, 0.f), 6.f) * msk;
            ov.z = fminf(fmaxf(s2, 0.f), 6.f) * msk;
            ov.w = fminf(fmaxf(s3, 0.f), 6.f) * msk;
        }

        if (i < CHUNK - 1) {
            *(float4*)&nxt[cell] = ov;
            __syncthreads();
            float* tmp = cur; cur = nxt; nxt = tmp;
        }
        // store AFTER the barrier: retires in the shadow of the next step
        if (wOK)
            *(float4*)(gbase + (size_t)i * BHW_) = ov;
    }
}

// ---------------------------------------------------------------------------
// Fuse kernel, 2 pixels/thread (identical to round-2/4 — unchanged for
// attribution).
// ---------------------------------------------------------------------------
__global__ __launch_bounds__(256) void fuse_kernel(
    const float* __restrict__ ys,      // (C, BHW)
    const float* __restrict__ pw_w,    // (P, C)
    const float* __restrict__ gamma,
    const float* __restrict__ beta,
    const float* __restrict__ mean,
    const float* __restrict__ var,
    const float* __restrict__ conv_w,  // (1, P)
    float* __restrict__ out)           // (BHW)
{
    __shared__ float As[C_ * P_];      // As[c*64 + p] = pw_w[p][c] * scale[p]
    __shared__ float bias_s[P_];
    __shared__ float cw_s[P_];

    const int tid = threadIdx.x;

    for (int idx = tid; idx < C_ * P_; idx += 256) {
        int p = idx & 63;
        int c = idx >> 6;
        float scale = gamma[p] / sqrtf(var[p] + BN_EPS);
        As[idx] = pw_w[p * C_ + c] * scale;
    }
    if (tid < P_) {
        float scale = gamma[tid] / sqrtf(var[tid] + BN_EPS);
        bias_s[tid] = beta[tid] - mean[tid] * scale;
        cw_s[tid]   = conv_w[tid];
    }
    __syncthreads();

    const size_t n0 = (size_t)blockIdx.x * 512 + tid;
    const size_t n1 = n0 + 256;

    float h0[P_], h1[P_];
#pragma unroll
    for (int p = 0; p < P_; ++p) { h0[p] = 0.f; h1[p] = 0.f; }

#pragma unroll 2
    for (int c = 0; c < C_; ++c) {
        float y0 = ys[(size_t)c * BHW_ + n0];
        float y1 = ys[(size_t)c * BHW_ + n1];
        const float* arow = &As[c * P_];
#pragma unroll
        for (int p = 0; p < P_; ++p) {
            float av = arow[p];
            h0[p] = fmaf(av, y0, h0[p]);
            h1[p] = fmaf(av, y1, h1[p]);
        }
    }

    float acc0 = 0.f, acc1 = 0.f;
#pragma unroll
    for (int p = 0; p < P_; ++p) {
        float v0 = fminf(fmaxf(h0[p] + bias_s[p], 0.f), 6.f);
        float v1 = fminf(fmaxf(h1[p] + bias_s[p], 0.f), 6.f);
        acc0 = fmaf(cw_s[p], v0, acc0);
        acc1 = fmaf(cw_s[p], v1, acc1);
    }
    out[n0] = acc0;
    out[n1] = acc1;
}

// ---------------------------------------------------------------------------
extern "C" void kernel_launch(void* const* d_in, const int* in_sizes, int n_in,
                              void* d_out, int out_size, void* d_ws, size_t ws_size,
                              hipStream_t stream) {
    const float* x      = (const float*)d_in[0];   // (B,C,H,W) — only chan 0 used
    const float* dw_w   = (const float*)d_in[1];   // (C,3,3)
    const float* pw_w   = (const float*)d_in[2];   // (P,C)
    const float* gamma  = (const float*)d_in[3];
    const float* beta   = (const float*)d_in[4];
    const float* mean   = (const float*)d_in[5];
    const float* var    = (const float*)d_in[6];
    const float* conv_w = (const float*)d_in[7];   // (1,P)
    float* out = (float*)d_out;

    float* ys = (float*)d_ws;                      // (C, B, H, W) fp32 = 128 MiB

    dim3 cgrid(W_ / 32, H_ / 32, B_);              // 8,8,8 = 512 blocks

    // chunk 0: seeded by x[:, 0]
    chain_kernel<<<cgrid, 1024, 0, stream>>>(
        x, (size_t)C_ * H_ * W_, dw_w, ys, 0);

    // chunks 1..3: seeded by ys[c0-1]
    for (int k = 1; k < C_ / CHUNK; ++k) {
        int c0 = k * CHUNK;
        chain_kernel<<<cgrid, 1024, 0, stream>>>(
            ys + (size_t)(c0 - 1) * BHW_, (size_t)H_ * W_,
            dw_w + c0 * 9, ys, c0);
    }

    // fused pointwise + BN + ReLU6 + final 1x1  (2 px/thread)
    fuse_kernel<<<BHW_ / 512, 256, 0, stream>>>(
        ys, pw_w, gamma, beta, mean, var, conv_w, out);
}